// Round 6
// baseline (781.227 us; speedup 1.0000x reference)
//
#include <hip/hip_runtime.h>
#include <hip/hip_cooperative_groups.h>
#include <cmath>

#ifndef M_PI
#define M_PI 3.14159265358979323846
#endif

namespace cg = cooperative_groups;

static constexpr int CH     = 128;
static constexpr int NBATCH = 64;
static constexpr int HWSZ   = 3136;
static constexpr int HW4    = 784;
static constexpr int PARTS  = 8;                 // parts per channel
static constexpr int SLPP   = NBATCH / PARTS;    // 8 batch slices per part
static constexpr int KTOP   = 10;
static constexpr float EPSV = 1e-5f;
static constexpr int LBUF   = 4096;              // per-block collect buffer
static constexpr int CAP    = 8192;              // per-channel candidate cap
static constexpr float ALPHA = 0.55f;            // exact-maxdev threshold factor
static constexpr float FBIG = 3.402823e38f;

#define CSA(a,b) { float lo_=fminf(a,b), hi_=fmaxf(a,b); a=lo_; b=hi_; }

union SharedU {           // phases are barrier-separated; reuse one block
  float buf[LBUF];        // P3 collect       (16 KB)
  float ls[CAP];          // P5 finalize      (32 KB)
  float shT[KTOP * 256];  // P4 rescue        (10 KB)
};

// 1024 blocks x 256 threads = 4 blocks/CU on 256 CUs (co-resident).
__global__ __launch_bounds__(256, 4) void k_fused(
    const float* __restrict__ x, const float* __restrict__ weight,
    const float* __restrict__ bias, float* __restrict__ out,
    float* sums, float* mins, float* maxs,
    unsigned* cnt, unsigned* ovf, float* cand, float* tops,
    float* swg, float* sbg, float constv) {
  cg::grid_group grid = cg::this_grid();
  __shared__ SharedU u;
  __shared__ float shs[4], shn[4], shx[4];
  __shared__ float rwv[4];
  __shared__ int   rwi[4];
  __shared__ unsigned lcnt, gbase;

  const int bid  = blockIdx.x;
  const int c    = bid & (CH - 1);
  const int part = bid >> 7;        // 0..7
  const int tid  = threadIdx.x;
  const int lane = tid & 63, wid = tid >> 6;
  const float4* x4 = reinterpret_cast<const float4*>(x);

  if (part == 0 && tid == 0) { cnt[c] = 0u; ovf[c] = 0u; }

  // ---- P1: sum / min / max sweep (cold HBM read) ----
  float s = 0.f, mn = FBIG, mx = -FBIG;
  for (int sl = 0; sl < SLPP; ++sl) {
    const size_t base = (size_t)((part * SLPP + sl) * CH + c) * HW4;
    for (int i = tid; i < HW4; i += 256) {
      float4 v = x4[base + i];
      s += (v.x + v.y) + (v.z + v.w);
      mn = fminf(mn, fminf(fminf(v.x, v.y), fminf(v.z, v.w)));
      mx = fmaxf(mx, fmaxf(fmaxf(v.x, v.y), fmaxf(v.z, v.w)));
    }
  }
  for (int off = 32; off; off >>= 1) {
    s  += __shfl_down(s, off);
    mn  = fminf(mn, __shfl_down(mn, off));
    mx  = fmaxf(mx, __shfl_down(mx, off));
  }
  if (lane == 0) { shs[wid] = s; shn[wid] = mn; shx[wid] = mx; }
  __syncthreads();
  if (tid == 0) {
    sums[part * CH + c] = (shs[0] + shs[1]) + (shs[2] + shs[3]);
    mins[part * CH + c] = fminf(fminf(shn[0], shn[1]), fminf(shn[2], shn[3]));
    maxs[part * CH + c] = fmaxf(fmaxf(shx[0], shx[1]), fmaxf(shx[2], shx[3]));
  }
  __threadfence();
  grid.sync();

  // ---- P2: every block redundantly computes exact mu, tau for its channel ----
  float acc = 0.f, cmn = FBIG, cmx = -FBIG;
  #pragma unroll
  for (int p = 0; p < PARTS; ++p) {
    acc += sums[p * CH + c];
    cmn  = fminf(cmn, mins[p * CH + c]);
    cmx  = fmaxf(cmx, maxs[p * CH + c]);
  }
  const float mu  = acc * (1.0f / ((float)NBATCH * (float)HWSZ));
  const float tau = ALPHA * fmaxf(cmx - mu, mu - cmn);

  // ---- P3: collect devs >= tau (L3-hot re-read), LDS-buffered ----
  if (tid == 0) lcnt = 0u;
  __syncthreads();
  for (int sl = 0; sl < SLPP; ++sl) {
    const size_t base = (size_t)((part * SLPP + sl) * CH + c) * HW4;
    for (int i = tid; i < HW4; i += 256) {
      float4 v = x4[base + i];
      float d0 = fabsf(v.x - mu), d1 = fabsf(v.y - mu);
      float d2 = fabsf(v.z - mu), d3 = fabsf(v.w - mu);
      if (d0 >= tau) { unsigned p = atomicAdd(&lcnt, 1u); if (p < LBUF) u.buf[p] = d0; }
      if (d1 >= tau) { unsigned p = atomicAdd(&lcnt, 1u); if (p < LBUF) u.buf[p] = d1; }
      if (d2 >= tau) { unsigned p = atomicAdd(&lcnt, 1u); if (p < LBUF) u.buf[p] = d2; }
      if (d3 >= tau) { unsigned p = atomicAdd(&lcnt, 1u); if (p < LBUF) u.buf[p] = d3; }
    }
  }
  __syncthreads();
  const unsigned nl = lcnt;
  if (tid == 0) {
    gbase = atomicAdd(&cnt[c], nl);
    if (nl > (unsigned)LBUF) ovf[c] = 1u;
  }
  __syncthreads();
  {
    const unsigned nw = nl < (unsigned)LBUF ? nl : (unsigned)LBUF;
    float* cc = cand + (size_t)c * CAP;
    const unsigned gb = gbase;
    for (unsigned i = tid; i < nw; i += 256) {
      const unsigned p = gb + i;
      if (p < (unsigned)CAP) cc[p] = u.buf[i];
    }
  }
  __threadfence();
  grid.sync();

  // ---- P4: rescue (exact per-part top-10) only for bad channels ----
  const unsigned nc = cnt[c];
  const bool bad = (nc < (unsigned)KTOP) || (nc > (unsigned)CAP) || (ovf[c] != 0u);
  if (bad) {
    float t0=-1.f,t1=-1.f,t2=-1.f,t3=-1.f,t4=-1.f,
          t5=-1.f,t6=-1.f,t7=-1.f,t8=-1.f,t9=-1.f;
    for (int sl = 0; sl < SLPP; ++sl) {
      const size_t base = (size_t)((part * SLPP + sl) * CH + c) * HW4;
      for (int i = tid; i < HW4; i += 256) {
        float4 v = x4[base + i];
        float d0 = fabsf(v.x - mu), d1 = fabsf(v.y - mu);
        float d2 = fabsf(v.z - mu), d3 = fabsf(v.w - mu);
        if (d0 > t0) { t0=d0; CSA(t0,t1);CSA(t1,t2);CSA(t2,t3);CSA(t3,t4);CSA(t4,t5);CSA(t5,t6);CSA(t6,t7);CSA(t7,t8);CSA(t8,t9); }
        if (d1 > t0) { t0=d1; CSA(t0,t1);CSA(t1,t2);CSA(t2,t3);CSA(t3,t4);CSA(t4,t5);CSA(t5,t6);CSA(t6,t7);CSA(t7,t8);CSA(t8,t9); }
        if (d2 > t0) { t0=d2; CSA(t0,t1);CSA(t1,t2);CSA(t2,t3);CSA(t3,t4);CSA(t4,t5);CSA(t5,t6);CSA(t6,t7);CSA(t7,t8);CSA(t8,t9); }
        if (d3 > t0) { t0=d3; CSA(t0,t1);CSA(t1,t2);CSA(t2,t3);CSA(t3,t4);CSA(t4,t5);CSA(t5,t6);CSA(t6,t7);CSA(t7,t8);CSA(t8,t9); }
      }
    }
    u.shT[0*256+tid]=t0; u.shT[1*256+tid]=t1; u.shT[2*256+tid]=t2; u.shT[3*256+tid]=t3;
    u.shT[4*256+tid]=t4; u.shT[5*256+tid]=t5; u.shT[6*256+tid]=t6; u.shT[7*256+tid]=t7;
    u.shT[8*256+tid]=t8; u.shT[9*256+tid]=t9;
    __syncthreads();
    for (int it = 0; it < KTOP; ++it) {
      float best = -1.f; int bi = 0;
      #pragma unroll
      for (int j = 0; j < KTOP; ++j) {
        float v = u.shT[j*256 + tid];
        if (v > best) { best = v; bi = j*256 + tid; }
      }
      for (int off = 32; off; off >>= 1) {
        float ov = __shfl_down(best, off);
        int   oi = __shfl_down(bi, off);
        if (ov > best) { best = ov; bi = oi; }
      }
      if (lane == 0) { rwv[wid] = best; rwi[wid] = bi; }
      __syncthreads();
      if (tid == 0) {
        float bb = rwv[0]; int bbi = rwi[0];
        for (int w = 1; w < 4; ++w) if (rwv[w] > bb) { bb = rwv[w]; bbi = rwi[w]; }
        tops[(part * CH + c) * KTOP + it] = bb;
        u.shT[bbi] = -1.f;
      }
      __syncthreads();
    }
  }
  __threadfence();
  grid.sync();

  // ---- P5: finalize (128 blocks, one per channel) ----
  if (part == 0) {
    int m;
    if (!bad) {
      m = (int)nc;
      const float* cc = cand + (size_t)c * CAP;
      for (int i = tid; i < m; i += 256) u.ls[i] = cc[i];
    } else {
      m = PARTS * KTOP;
      for (int i = tid; i < m; i += 256) {
        const int p = i / KTOP, it = i - p * KTOP;
        u.ls[i] = tops[(p * CH + c) * KTOP + it];
      }
    }
    __syncthreads();
    float totl = 0.f;
    for (int it = 0; it < KTOP; ++it) {
      float best = -1.f; int bi = 0;
      for (int i = tid; i < m; i += 256) {
        float v = u.ls[i];
        if (v > best) { best = v; bi = i; }
      }
      for (int off = 32; off; off >>= 1) {
        float ov = __shfl_down(best, off);
        int   oi = __shfl_down(bi, off);
        if (ov > best) { best = ov; bi = oi; }
      }
      if (lane == 0) { rwv[wid] = best; rwi[wid] = bi; }
      __syncthreads();
      if (tid == 0) {
        float bb = rwv[0]; int bbi = rwi[0];
        for (int w = 1; w < 4; ++w) if (rwv[w] > bb) { bb = rwv[w]; bbi = rwi[w]; }
        totl += bb;
        u.ls[bbi] = -1.f;
      }
      __syncthreads();
    }
    if (tid == 0) {
      const float mtk = totl * (1.0f / KTOP) * constv;
      const float inv = 1.f / (mtk + EPSV);
      const float w   = inv * weight[c];
      swg[c] = w;
      sbg[c] = bias[c] - mu * w;
    }
  }
  __threadfence();
  grid.sync();

  // ---- P6: affine (L3-hot read + HBM write) ----
  const float w = swg[c], b = sbg[c];
  float4* o4 = reinterpret_cast<float4*>(out);
  for (int sl = 0; sl < SLPP; ++sl) {
    const size_t base = (size_t)((part * SLPP + sl) * CH + c) * HW4;
    for (int i = tid; i < HW4; i += 256) {
      float4 v = x4[base + i];
      float4 r;
      r.x = fmaf(v.x, w, b);
      r.y = fmaf(v.y, w, b);
      r.z = fmaf(v.z, w, b);
      r.w = fmaf(v.w, w, b);
      o4[base + i] = r;
    }
  }
}

extern "C" void kernel_launch(void* const* d_in, const int* in_sizes, int n_in,
                              void* d_out, int out_size, void* d_ws, size_t ws_size,
                              hipStream_t stream) {
  const float* x      = (const float*)d_in[0];
  const float* weight = (const float*)d_in[1];
  const float* bias   = (const float*)d_in[2];
  float* out = (float*)d_out;
  float* ws  = (float*)d_ws;

  // ws layout (floats): total ~ 12.6K + CH*CAP(1M) floats ~= 4.2 MB
  float*    sums = ws;                          // PARTS*CH = 1024
  float*    mins = sums + PARTS * CH;           // 1024
  float*    maxs = mins + PARTS * CH;           // 1024
  float*    swg  = maxs + PARTS * CH;           // 128
  float*    sbg  = swg + CH;                    // 128
  float*    tops = sbg + CH;                    // PARTS*CH*KTOP = 10240
  unsigned* cnt  = (unsigned*)(tops + PARTS * CH * KTOP); // 128
  unsigned* ovf  = cnt + CH;                    // 128
  float*    cand = (float*)(ovf + CH);          // CH*CAP

  const double M = (double)NBATCH * (double)HWSZ;
  float constv =
      (float)(0.5 * (1.0 + sqrt(M_PI * log(4.0))) / sqrt(2.0 * log(M)));

  void* args[] = {(void*)&x, (void*)&weight, (void*)&bias, (void*)&out,
                  (void*)&sums, (void*)&mins, (void*)&maxs,
                  (void*)&cnt, (void*)&ovf, (void*)&cand, (void*)&tops,
                  (void*)&swg, (void*)&sbg, (void*)&constv};
  hipLaunchCooperativeKernel((const void*)k_fused, dim3(PARTS * CH), dim3(256),
                             args, 0, stream);
}

// Round 7
// 76.169 us; speedup vs baseline: 10.2566x; 10.2566x over previous
//
#include <hip/hip_runtime.h>
#include <cmath>

#ifndef M_PI
#define M_PI 3.14159265358979323846
#endif

static constexpr int CH     = 128;
static constexpr int NBATCH = 64;
static constexpr int HWSZ   = 3136;
static constexpr int HW4    = 784;
static constexpr int PARTS  = 16;
static constexpr int SLPP   = NBATCH / PARTS;   // 4
static constexpr int KTOP   = 10;
static constexpr float EPSV = 1e-5f;
static constexpr int LBUF   = 4096;             // k_main per-block LDS buffer
static constexpr int CAPMAX = 8192;             // k_out LDS candidate capacity

typedef float f32x4 __attribute__((ext_vector_type(4)));

#define CSA(a,b) { float lo_=fminf(a,b), hi_=fmaxf(a,b); a=lo_; b=hi_; }
#define CHAIN(d) if ((d) > t0) { t0=(d); CSA(t0,t1);CSA(t1,t2);CSA(t2,t3); \
  CSA(t3,t4);CSA(t4,t5);CSA(t5,t6);CSA(t6,t7);CSA(t7,t8);CSA(t8,t9); }

// ---------------------------------------------------------------------------
// k_stats: per channel, CONTIGUOUS 2-slice sample (n=0, n=32) -> mu_hat, tau.
// Also zeroes cnt/ovf.  grid = CH blocks, 256 threads.  ~3 us.
// ---------------------------------------------------------------------------
__global__ __launch_bounds__(256) void k_stats(const float* __restrict__ x,
                                               float* __restrict__ muhat,
                                               float* __restrict__ tauv,
                                               unsigned* __restrict__ cnt,
                                               unsigned* __restrict__ ovf,
                                               float tauf) {
  const int c = blockIdx.x, tid = threadIdx.x;
  const int lane = tid & 63, wid = tid >> 6;
  const float4* x4 = reinterpret_cast<const float4*>(x);
  const size_t b0 = (size_t)c * HW4;                      // slice n=0
  const size_t b1 = (size_t)(32 * CH + c) * HW4;          // slice n=32
  __shared__ float sh[4];
  __shared__ float smu;

  float s = 0.f;
  for (int i = tid; i < HW4; i += 256) {
    float4 a = x4[b0 + i], b = x4[b1 + i];
    s += ((a.x + a.y) + (a.z + a.w)) + ((b.x + b.y) + (b.z + b.w));
  }
  for (int off = 32; off; off >>= 1) s += __shfl_down(s, off);
  if (lane == 0) sh[wid] = s;
  __syncthreads();
  if (tid == 0) smu = ((sh[0] + sh[1]) + (sh[2] + sh[3])) * (1.f / (2.f * HWSZ));
  __syncthreads();
  const float mu = smu;

  float m = 0.f;
  for (int i = tid; i < HW4; i += 256) {
    float4 a = x4[b0 + i], b = x4[b1 + i];   // L2-hot re-read
    m = fmaxf(m, fmaxf(fmaxf(fabsf(a.x - mu), fabsf(a.y - mu)),
                       fmaxf(fabsf(a.z - mu), fabsf(a.w - mu))));
    m = fmaxf(m, fmaxf(fmaxf(fabsf(b.x - mu), fabsf(b.y - mu)),
                       fmaxf(fabsf(b.z - mu), fabsf(b.w - mu))));
  }
  for (int off = 32; off; off >>= 1) m = fmaxf(m, __shfl_down(m, off));
  if (lane == 0) sh[wid] = m;
  __syncthreads();
  if (tid == 0) {
    const float mm = fmaxf(fmaxf(sh[0], sh[1]), fmaxf(sh[2], sh[3]));
    muhat[c] = mu;
    tauv[c]  = tauf * mm;
    cnt[c]   = 0u;
    ovf[c]   = 0u;
  }
}

// ---------------------------------------------------------------------------
// k_main: ONE sweep of x: exact partial sums + candidate collection
// (raw v with |v - mu_hat| >= tau), LDS-buffered, 1 global atomic per block.
// grid = PARTS*CH = 2048 blocks, 256 threads.
// ---------------------------------------------------------------------------
__global__ __launch_bounds__(256) void k_main(const float* __restrict__ x,
                                              const float* __restrict__ muhat,
                                              const float* __restrict__ tauv,
                                              float* __restrict__ sums,
                                              unsigned* __restrict__ cnt,
                                              unsigned* __restrict__ ovf,
                                              float* __restrict__ cand,
                                              int cap) {
  __shared__ float buf[LBUF];
  __shared__ unsigned lcnt, gbase;
  __shared__ float shs[4];
  const int bid  = blockIdx.x;
  const int c    = bid & (CH - 1);
  const int part = bid >> 7;
  const int tid  = threadIdx.x;
  if (tid == 0) lcnt = 0u;
  __syncthreads();

  const float mu = muhat[c], t = tauv[c];
  const float4* x4 = reinterpret_cast<const float4*>(x);

  float s = 0.f;
  for (int sl = 0; sl < SLPP; ++sl) {
    const size_t base = (size_t)((part * SLPP + sl) * CH + c) * HW4;
    for (int i = tid; i < HW4; i += 256) {
      float4 v = x4[base + i];
      s += (v.x + v.y) + (v.z + v.w);
      if (fabsf(v.x - mu) >= t) { unsigned p = atomicAdd(&lcnt, 1u); if (p < LBUF) buf[p] = v.x; }
      if (fabsf(v.y - mu) >= t) { unsigned p = atomicAdd(&lcnt, 1u); if (p < LBUF) buf[p] = v.y; }
      if (fabsf(v.z - mu) >= t) { unsigned p = atomicAdd(&lcnt, 1u); if (p < LBUF) buf[p] = v.z; }
      if (fabsf(v.w - mu) >= t) { unsigned p = atomicAdd(&lcnt, 1u); if (p < LBUF) buf[p] = v.w; }
    }
  }
  for (int off = 32; off; off >>= 1) s += __shfl_down(s, off);
  const int lane = tid & 63, wid = tid >> 6;
  if (lane == 0) shs[wid] = s;
  __syncthreads();

  if (tid == 0) {
    sums[part * CH + c] = (shs[0] + shs[1]) + (shs[2] + shs[3]);
    gbase = atomicAdd(&cnt[c], lcnt);
    if (lcnt > (unsigned)LBUF) ovf[c] = 1u;
  }
  __syncthreads();

  const unsigned nw = lcnt < (unsigned)LBUF ? lcnt : (unsigned)LBUF;
  const unsigned gb = gbase;
  float* cc = cand + (size_t)c * cap;
  for (unsigned i = tid; i < nw; i += 256) {
    const unsigned p = gb + i;
    if (p < (unsigned)cap) cc[p] = buf[i];
  }
}

// ---------------------------------------------------------------------------
// k_out: fused select + rescue + affine.  grid = PARTS*CH, 256 threads.
// Each block redundantly: exact mu from partials; top-10 from its channel's
// candidates (LDS); fold (w,b); then affine over its 4 slices (nt stores).
// ---------------------------------------------------------------------------
__global__ __launch_bounds__(256) void k_out(const float* __restrict__ x,
                                             const float* __restrict__ sums,
                                             const unsigned* __restrict__ cnt,
                                             const unsigned* __restrict__ ovf,
                                             const float* __restrict__ cand,
                                             const float* __restrict__ weight,
                                             const float* __restrict__ bias,
                                             float* __restrict__ out,
                                             int cap, float constv) {
  __shared__ float ls[CAPMAX];      // 32 KB
  __shared__ float rwv[4];
  __shared__ int   rwi[4];
  const int bid  = blockIdx.x;
  const int c    = bid & (CH - 1);
  const int part = bid >> 7;
  const int tid  = threadIdx.x;
  const int lane = tid & 63, wid = tid >> 6;
  const float4* x4 = reinterpret_cast<const float4*>(x);

  // exact mean (every thread redundantly; 16 L2-broadcast loads)
  float acc = 0.f;
  #pragma unroll
  for (int p = 0; p < PARTS; ++p) acc += sums[p * CH + c];
  const float mu = acc * (1.0f / ((float)NBATCH * (float)HWSZ));

  const unsigned n = cnt[c];
  const bool good = (n >= (unsigned)KTOP) && (n <= (unsigned)cap) &&
                    (n <= (unsigned)CAPMAX) && (ovf[c] == 0u);
  int m;
  if (good) {
    m = (int)n;
    const float* cc = cand + (size_t)c * cap;
    for (int i = tid; i < m; i += 256) ls[i] = fabsf(cc[i] - mu);
  } else {
    // rescue: full-channel per-thread top-10 chain (never fires normally)
    float t0=-1.f,t1=-1.f,t2=-1.f,t3=-1.f,t4=-1.f,
          t5=-1.f,t6=-1.f,t7=-1.f,t8=-1.f,t9=-1.f;
    for (int sl = 0; sl < NBATCH; ++sl) {
      const size_t base = (size_t)(sl * CH + c) * HW4;
      for (int i = tid; i < HW4; i += 256) {
        float4 v = x4[base + i];
        float d0 = fabsf(v.x - mu), d1 = fabsf(v.y - mu);
        float d2 = fabsf(v.z - mu), d3 = fabsf(v.w - mu);
        CHAIN(d0); CHAIN(d1); CHAIN(d2); CHAIN(d3);
      }
    }
    ls[0*256+tid]=t0; ls[1*256+tid]=t1; ls[2*256+tid]=t2; ls[3*256+tid]=t3;
    ls[4*256+tid]=t4; ls[5*256+tid]=t5; ls[6*256+tid]=t6; ls[7*256+tid]=t7;
    ls[8*256+tid]=t8; ls[9*256+tid]=t9;
    m = KTOP * 256;
  }
  __syncthreads();

  // 10-round max extraction over ls[0..m)
  float tot = 0.f;
  for (int it = 0; it < KTOP; ++it) {
    float best = -1.f; int bi = 0;
    for (int i = tid; i < m; i += 256) {
      float v = ls[i];
      if (v > best) { best = v; bi = i; }
    }
    for (int off = 32; off; off >>= 1) {
      float ov = __shfl_down(best, off);
      int   oi = __shfl_down(bi, off);
      if (ov > best) { best = ov; bi = oi; }
    }
    if (lane == 0) { rwv[wid] = best; rwi[wid] = bi; }
    __syncthreads();
    if (tid == 0) {
      float bb = rwv[0]; int bbi = rwi[0];
      for (int w = 1; w < 4; ++w) if (rwv[w] > bb) { bb = rwv[w]; bbi = rwi[w]; }
      tot += bb;
      ls[bbi] = -1.f;
    }
    __syncthreads();
  }

  if (tid == 0) {
    const float mtk = tot * (1.0f / KTOP) * constv;
    const float inv = 1.f / (mtk + EPSV);
    const float w   = inv * weight[c];
    rwv[0] = w;
    rwv[1] = bias[c] - mu * w;
  }
  __syncthreads();
  const float w = rwv[0], b = rwv[1];

  // affine over this block's 4 slices; nt stores keep x L3-resident
  f32x4* o4 = reinterpret_cast<f32x4*>(out);
  for (int sl = 0; sl < SLPP; ++sl) {
    const size_t base = (size_t)((part * SLPP + sl) * CH + c) * HW4;
    for (int i = tid; i < HW4; i += 256) {
      float4 v = x4[base + i];
      f32x4 r = { fmaf(v.x, w, b), fmaf(v.y, w, b),
                  fmaf(v.z, w, b), fmaf(v.w, w, b) };
      __builtin_nontemporal_store(r, &o4[base + i]);
    }
  }
}

extern "C" void kernel_launch(void* const* d_in, const int* in_sizes, int n_in,
                              void* d_out, int out_size, void* d_ws, size_t ws_size,
                              hipStream_t stream) {
  const float* x      = (const float*)d_in[0];
  const float* weight = (const float*)d_in[1];
  const float* bias   = (const float*)d_in[2];
  float* out = (float*)d_out;
  float* ws  = (float*)d_ws;

  // ws layout (floats)
  float*    sums  = ws;                         // PARTS*CH = 2048
  float*    muhat = sums + PARTS * CH;          // 128
  float*    tauv  = muhat + CH;                 // 128
  unsigned* cnt   = (unsigned*)(tauv + CH);     // 128
  unsigned* ovf   = cnt + CH;                   // 128
  float*    cand  = (float*)(ovf + CH);         // CH*cap
  const size_t FIXED = (size_t)((float*)cand - ws);

  const size_t avail = ws_size / 4;
  int cap; float tauf;
  if      (avail >= FIXED + (size_t)CH * 8192) { cap = 8192; tauf = 0.72f; }
  else if (avail >= FIXED + (size_t)CH * 2048) { cap = 2048; tauf = 0.85f; }
  else                                         { cap = 1024; tauf = 0.90f; }

  const double M = (double)NBATCH * (double)HWSZ;
  const float constv =
      (float)(0.5 * (1.0 + sqrt(M_PI * log(4.0))) / sqrt(2.0 * log(M)));

  k_stats<<<CH, 256, 0, stream>>>(x, muhat, tauv, cnt, ovf, tauf);
  k_main<<<PARTS * CH, 256, 0, stream>>>(x, muhat, tauv, sums, cnt, ovf, cand, cap);
  k_out<<<PARTS * CH, 256, 0, stream>>>(x, sums, cnt, ovf, cand, weight, bias,
                                        out, cap, constv);
}

// Round 8
// 75.908 us; speedup vs baseline: 10.2918x; 1.0034x over previous
//
#include <hip/hip_runtime.h>
#include <cmath>

#ifndef M_PI
#define M_PI 3.14159265358979323846
#endif

static constexpr int CH     = 128;
static constexpr int NBATCH = 64;
static constexpr int HWSZ   = 3136;
static constexpr int HW4    = 784;
static constexpr int PARTS  = 16;
static constexpr int SLPP   = NBATCH / PARTS;   // 4
static constexpr int KTOP   = 10;
static constexpr float EPSV = 1e-5f;
static constexpr int LBUF   = 4096;             // k_main per-block LDS buffer
static constexpr int CAPMAX = 8192;             // k_select LDS candidate capacity

typedef float f32x4 __attribute__((ext_vector_type(4)));

#define CSA(a,b) { float lo_=fminf(a,b), hi_=fmaxf(a,b); a=lo_; b=hi_; }
#define CHAIN(d) if ((d) > t0) { t0=(d); CSA(t0,t1);CSA(t1,t2);CSA(t2,t3); \
  CSA(t3,t4);CSA(t4,t5);CSA(t5,t6);CSA(t6,t7);CSA(t7,t8);CSA(t8,t9); }

// ---------------------------------------------------------------------------
// k_stats: per channel, CONTIGUOUS 2-slice sample (n=0, n=32) -> mu_hat, tau.
// Uniform per-channel tau => cnt>=10 certifies exact top-10 coverage.
// Also zeroes cnt/ovf.  grid = CH blocks, 256 threads.
// ---------------------------------------------------------------------------
__global__ __launch_bounds__(256) void k_stats(const float* __restrict__ x,
                                               float* __restrict__ muhat,
                                               float* __restrict__ tauv,
                                               unsigned* __restrict__ cnt,
                                               unsigned* __restrict__ ovf,
                                               float tauf) {
  const int c = blockIdx.x, tid = threadIdx.x;
  const int lane = tid & 63, wid = tid >> 6;
  const float4* x4 = reinterpret_cast<const float4*>(x);
  const size_t b0 = (size_t)c * HW4;                      // slice n=0
  const size_t b1 = (size_t)(32 * CH + c) * HW4;          // slice n=32
  __shared__ float sh[4];
  __shared__ float smu;

  float s = 0.f;
  for (int i = tid; i < HW4; i += 256) {
    float4 a = x4[b0 + i], b = x4[b1 + i];
    s += ((a.x + a.y) + (a.z + a.w)) + ((b.x + b.y) + (b.z + b.w));
  }
  for (int off = 32; off; off >>= 1) s += __shfl_down(s, off);
  if (lane == 0) sh[wid] = s;
  __syncthreads();
  if (tid == 0) smu = ((sh[0] + sh[1]) + (sh[2] + sh[3])) * (1.f / (2.f * HWSZ));
  __syncthreads();
  const float mu = smu;

  float m = 0.f;
  for (int i = tid; i < HW4; i += 256) {
    float4 a = x4[b0 + i], b = x4[b1 + i];   // L2-hot re-read
    m = fmaxf(m, fmaxf(fmaxf(fabsf(a.x - mu), fabsf(a.y - mu)),
                       fmaxf(fabsf(a.z - mu), fabsf(a.w - mu))));
    m = fmaxf(m, fmaxf(fmaxf(fabsf(b.x - mu), fabsf(b.y - mu)),
                       fmaxf(fabsf(b.z - mu), fabsf(b.w - mu))));
  }
  for (int off = 32; off; off >>= 1) m = fmaxf(m, __shfl_down(m, off));
  if (lane == 0) sh[wid] = m;
  __syncthreads();
  if (tid == 0) {
    const float mm = fmaxf(fmaxf(sh[0], sh[1]), fmaxf(sh[2], sh[3]));
    muhat[c] = mu;
    tauv[c]  = tauf * mm;
    cnt[c]   = 0u;
    ovf[c]   = 0u;
  }
}

// ---------------------------------------------------------------------------
// k_main: ONE sweep of x: exact partial sums + candidate collection
// (raw v with |v - mu_hat| >= tau), LDS-buffered, 1 global atomic per block.
// grid = PARTS*CH = 2048 blocks, 256 threads.
// ---------------------------------------------------------------------------
__global__ __launch_bounds__(256) void k_main(const float* __restrict__ x,
                                              const float* __restrict__ muhat,
                                              const float* __restrict__ tauv,
                                              float* __restrict__ sums,
                                              unsigned* __restrict__ cnt,
                                              unsigned* __restrict__ ovf,
                                              float* __restrict__ cand,
                                              int cap) {
  __shared__ float buf[LBUF];
  __shared__ unsigned lcnt, gbase;
  __shared__ float shs[4];
  const int bid  = blockIdx.x;
  const int c    = bid & (CH - 1);
  const int part = bid >> 7;
  const int tid  = threadIdx.x;
  if (tid == 0) lcnt = 0u;
  __syncthreads();

  const float mu = muhat[c], t = tauv[c];
  const float4* x4 = reinterpret_cast<const float4*>(x);

  float s = 0.f;
  for (int sl = 0; sl < SLPP; ++sl) {
    const size_t base = (size_t)((part * SLPP + sl) * CH + c) * HW4;
    for (int i = tid; i < HW4; i += 256) {
      float4 v = x4[base + i];
      s += (v.x + v.y) + (v.z + v.w);
      if (fabsf(v.x - mu) >= t) { unsigned p = atomicAdd(&lcnt, 1u); if (p < LBUF) buf[p] = v.x; }
      if (fabsf(v.y - mu) >= t) { unsigned p = atomicAdd(&lcnt, 1u); if (p < LBUF) buf[p] = v.y; }
      if (fabsf(v.z - mu) >= t) { unsigned p = atomicAdd(&lcnt, 1u); if (p < LBUF) buf[p] = v.z; }
      if (fabsf(v.w - mu) >= t) { unsigned p = atomicAdd(&lcnt, 1u); if (p < LBUF) buf[p] = v.w; }
    }
  }
  for (int off = 32; off; off >>= 1) s += __shfl_down(s, off);
  const int lane = tid & 63, wid = tid >> 6;
  if (lane == 0) shs[wid] = s;
  __syncthreads();

  if (tid == 0) {
    sums[part * CH + c] = (shs[0] + shs[1]) + (shs[2] + shs[3]);
    gbase = atomicAdd(&cnt[c], lcnt);
    if (lcnt > (unsigned)LBUF) ovf[c] = 1u;
  }
  __syncthreads();

  const unsigned nw = lcnt < (unsigned)LBUF ? lcnt : (unsigned)LBUF;
  const unsigned gb = gbase;
  float* cc = cand + (size_t)c * cap;
  for (unsigned i = tid; i < nw; i += 256) {
    const unsigned p = gb + i;
    if (p < (unsigned)cap) cc[p] = buf[i];
  }
}

// ---------------------------------------------------------------------------
// k_select: per channel: exact mu, top-10 of |v-mu| from candidates (LDS)
// or full-channel rescue; fold into (sw, sb).  grid = CH, 256 threads.
// ---------------------------------------------------------------------------
__global__ __launch_bounds__(256) void k_select(const float* __restrict__ x,
                                                const float* __restrict__ sums,
                                                const unsigned* __restrict__ cnt,
                                                const unsigned* __restrict__ ovf,
                                                const float* __restrict__ cand,
                                                const float* __restrict__ weight,
                                                const float* __restrict__ bias,
                                                float* __restrict__ swg,
                                                float* __restrict__ sbg,
                                                int cap, float constv) {
  __shared__ float ls[CAPMAX];      // 32 KB (128-block kernel; occupancy moot)
  __shared__ float rwv[4];
  __shared__ int   rwi[4];
  const int c   = blockIdx.x;
  const int tid = threadIdx.x;
  const int lane = tid & 63, wid = tid >> 6;
  const float4* x4 = reinterpret_cast<const float4*>(x);

  float acc = 0.f;
  #pragma unroll
  for (int p = 0; p < PARTS; ++p) acc += sums[p * CH + c];
  const float mu = acc * (1.0f / ((float)NBATCH * (float)HWSZ));

  const unsigned n = cnt[c];
  const bool good = (n >= (unsigned)KTOP) && (n <= (unsigned)cap) &&
                    (n <= (unsigned)CAPMAX) && (ovf[c] == 0u);
  int m;
  if (good) {
    m = (int)n;
    const float* cc = cand + (size_t)c * cap;
    for (int i = tid; i < m; i += 256) ls[i] = fabsf(cc[i] - mu);
  } else {
    // rescue: full-channel per-thread top-10 chain (certified never needed
    // when cnt>=10 with uniform tau; exact regardless)
    float t0=-1.f,t1=-1.f,t2=-1.f,t3=-1.f,t4=-1.f,
          t5=-1.f,t6=-1.f,t7=-1.f,t8=-1.f,t9=-1.f;
    for (int sl = 0; sl < NBATCH; ++sl) {
      const size_t base = (size_t)(sl * CH + c) * HW4;
      for (int i = tid; i < HW4; i += 256) {
        float4 v = x4[base + i];
        float d0 = fabsf(v.x - mu), d1 = fabsf(v.y - mu);
        float d2 = fabsf(v.z - mu), d3 = fabsf(v.w - mu);
        CHAIN(d0); CHAIN(d1); CHAIN(d2); CHAIN(d3);
      }
    }
    ls[0*256+tid]=t0; ls[1*256+tid]=t1; ls[2*256+tid]=t2; ls[3*256+tid]=t3;
    ls[4*256+tid]=t4; ls[5*256+tid]=t5; ls[6*256+tid]=t6; ls[7*256+tid]=t7;
    ls[8*256+tid]=t8; ls[9*256+tid]=t9;
    m = KTOP * 256;
  }
  __syncthreads();

  float tot = 0.f;
  for (int it = 0; it < KTOP; ++it) {
    float best = -1.f; int bi = 0;
    for (int i = tid; i < m; i += 256) {
      float v = ls[i];
      if (v > best) { best = v; bi = i; }
    }
    for (int off = 32; off; off >>= 1) {
      float ov = __shfl_down(best, off);
      int   oi = __shfl_down(bi, off);
      if (ov > best) { best = ov; bi = oi; }
    }
    if (lane == 0) { rwv[wid] = best; rwi[wid] = bi; }
    __syncthreads();
    if (tid == 0) {
      float bb = rwv[0]; int bbi = rwi[0];
      for (int w = 1; w < 4; ++w) if (rwv[w] > bb) { bb = rwv[w]; bbi = rwi[w]; }
      tot += bb;
      ls[bbi] = -1.f;
    }
    __syncthreads();
  }

  if (tid == 0) {
    const float mtk = tot * (1.0f / KTOP) * constv;
    const float inv = 1.f / (mtk + EPSV);
    const float w   = inv * weight[c];
    swg[c] = w;
    sbg[c] = bias[c] - mu * w;
  }
}

// ---------------------------------------------------------------------------
// k_affine: pure stream, zero LDS, full occupancy.  grid = PARTS*CH, 256 thr.
// out = fma(x, w[c], b[c]); NT stores (out never re-read).
// ---------------------------------------------------------------------------
__global__ __launch_bounds__(256) void k_affine(const float* __restrict__ x,
                                                const float* __restrict__ swg,
                                                const float* __restrict__ sbg,
                                                float* __restrict__ out) {
  const int bid  = blockIdx.x;
  const int c    = bid & (CH - 1);
  const int part = bid >> 7;
  const float w = swg[c], b = sbg[c];
  const float4* x4 = reinterpret_cast<const float4*>(x);
  f32x4* o4 = reinterpret_cast<f32x4*>(out);
  #pragma unroll
  for (int sl = 0; sl < SLPP; ++sl) {
    const size_t base = (size_t)((part * SLPP + sl) * CH + c) * HW4;
    for (int i = threadIdx.x; i < HW4; i += 256) {
      float4 v = x4[base + i];
      f32x4 r = { fmaf(v.x, w, b), fmaf(v.y, w, b),
                  fmaf(v.z, w, b), fmaf(v.w, w, b) };
      __builtin_nontemporal_store(r, &o4[base + i]);
    }
  }
}

extern "C" void kernel_launch(void* const* d_in, const int* in_sizes, int n_in,
                              void* d_out, int out_size, void* d_ws, size_t ws_size,
                              hipStream_t stream) {
  const float* x      = (const float*)d_in[0];
  const float* weight = (const float*)d_in[1];
  const float* bias   = (const float*)d_in[2];
  float* out = (float*)d_out;
  float* ws  = (float*)d_ws;

  // ws layout (floats)
  float*    sums  = ws;                         // PARTS*CH = 2048
  float*    muhat = sums + PARTS * CH;          // 128
  float*    tauv  = muhat + CH;                 // 128
  float*    swg   = tauv + CH;                  // 128
  float*    sbg   = swg + CH;                   // 128
  unsigned* cnt   = (unsigned*)(sbg + CH);      // 128
  unsigned* ovf   = cnt + CH;                   // 128
  float*    cand  = (float*)(ovf + CH);         // CH*cap
  const size_t FIXED = (size_t)((float*)cand - ws);

  const size_t avail = ws_size / 4;
  int cap; float tauf;
  if      (avail >= FIXED + (size_t)CH * 8192) { cap = 8192; tauf = 0.72f; }
  else if (avail >= FIXED + (size_t)CH * 2048) { cap = 2048; tauf = 0.85f; }
  else                                         { cap = 1024; tauf = 0.90f; }

  const double M = (double)NBATCH * (double)HWSZ;
  const float constv =
      (float)(0.5 * (1.0 + sqrt(M_PI * log(4.0))) / sqrt(2.0 * log(M)));

  k_stats<<<CH, 256, 0, stream>>>(x, muhat, tauv, cnt, ovf, tauf);
  k_main<<<PARTS * CH, 256, 0, stream>>>(x, muhat, tauv, sums, cnt, ovf, cand, cap);
  k_select<<<CH, 256, 0, stream>>>(x, sums, cnt, ovf, cand, weight, bias,
                                   swg, sbg, cap, constv);
  k_affine<<<PARTS * CH, 256, 0, stream>>>(x, swg, sbg, out);
}

// Round 9
// 75.769 us; speedup vs baseline: 10.3107x; 1.0018x over previous
//
#include <hip/hip_runtime.h>
#include <cmath>

#ifndef M_PI
#define M_PI 3.14159265358979323846
#endif

static constexpr int CH     = 128;
static constexpr int NBATCH = 64;
static constexpr int HWSZ   = 3136;
static constexpr int HW4    = 784;
static constexpr int PARTS  = 16;
static constexpr int SLPP   = NBATCH / PARTS;   // 4
static constexpr int KTOP   = 10;
static constexpr float EPSV = 1e-5f;
static constexpr int LBUF   = 4096;             // k_main per-block LDS buffer
static constexpr int CAPMAX = 8192;             // k_select LDS candidate capacity

#define CSA(a,b) { float lo_=fminf(a,b), hi_=fmaxf(a,b); a=lo_; b=hi_; }
#define CHAIN(d) if ((d) > t0) { t0=(d); CSA(t0,t1);CSA(t1,t2);CSA(t2,t3); \
  CSA(t3,t4);CSA(t4,t5);CSA(t5,t6);CSA(t6,t7);CSA(t7,t8);CSA(t8,t9); }

// ---------------------------------------------------------------------------
// k_stats: per channel, CONTIGUOUS 2-slice sample (n=0, n=32) -> mu_hat, tau.
// Uniform per-channel tau => cnt>=10 certifies exact top-10 coverage.
// Also zeroes cnt/ovf.  grid = CH blocks, 256 threads.
// ---------------------------------------------------------------------------
__global__ __launch_bounds__(256) void k_stats(const float* __restrict__ x,
                                               float* __restrict__ muhat,
                                               float* __restrict__ tauv,
                                               unsigned* __restrict__ cnt,
                                               unsigned* __restrict__ ovf,
                                               float tauf) {
  const int c = blockIdx.x, tid = threadIdx.x;
  const int lane = tid & 63, wid = tid >> 6;
  const float4* x4 = reinterpret_cast<const float4*>(x);
  const size_t b0 = (size_t)c * HW4;                      // slice n=0
  const size_t b1 = (size_t)(32 * CH + c) * HW4;          // slice n=32
  __shared__ float sh[4];
  __shared__ float smu;

  float s = 0.f;
  for (int i = tid; i < HW4; i += 256) {
    float4 a = x4[b0 + i], b = x4[b1 + i];
    s += ((a.x + a.y) + (a.z + a.w)) + ((b.x + b.y) + (b.z + b.w));
  }
  for (int off = 32; off; off >>= 1) s += __shfl_down(s, off);
  if (lane == 0) sh[wid] = s;
  __syncthreads();
  if (tid == 0) smu = ((sh[0] + sh[1]) + (sh[2] + sh[3])) * (1.f / (2.f * HWSZ));
  __syncthreads();
  const float mu = smu;

  float m = 0.f;
  for (int i = tid; i < HW4; i += 256) {
    float4 a = x4[b0 + i], b = x4[b1 + i];   // L2-hot re-read
    m = fmaxf(m, fmaxf(fmaxf(fabsf(a.x - mu), fabsf(a.y - mu)),
                       fmaxf(fabsf(a.z - mu), fabsf(a.w - mu))));
    m = fmaxf(m, fmaxf(fmaxf(fabsf(b.x - mu), fabsf(b.y - mu)),
                       fmaxf(fabsf(b.z - mu), fabsf(b.w - mu))));
  }
  for (int off = 32; off; off >>= 1) m = fmaxf(m, __shfl_down(m, off));
  if (lane == 0) sh[wid] = m;
  __syncthreads();
  if (tid == 0) {
    const float mm = fmaxf(fmaxf(sh[0], sh[1]), fmaxf(sh[2], sh[3]));
    muhat[c] = mu;
    tauv[c]  = tauf * mm;
    cnt[c]   = 0u;
    ovf[c]   = 0u;
  }
}

// ---------------------------------------------------------------------------
// k_main: ONE sweep of x: exact partial sums + candidate collection
// (raw v with |v - mu_hat| >= tau), LDS-buffered, 1 global atomic per block.
// grid = PARTS*CH = 2048 blocks, 256 threads.
// ---------------------------------------------------------------------------
__global__ __launch_bounds__(256) void k_main(const float* __restrict__ x,
                                              const float* __restrict__ muhat,
                                              const float* __restrict__ tauv,
                                              float* __restrict__ sums,
                                              unsigned* __restrict__ cnt,
                                              unsigned* __restrict__ ovf,
                                              float* __restrict__ cand,
                                              int cap) {
  __shared__ float buf[LBUF];
  __shared__ unsigned lcnt, gbase;
  __shared__ float shs[4];
  const int bid  = blockIdx.x;
  const int c    = bid & (CH - 1);
  const int part = bid >> 7;
  const int tid  = threadIdx.x;
  if (tid == 0) lcnt = 0u;
  __syncthreads();

  const float mu = muhat[c], t = tauv[c];
  const float4* x4 = reinterpret_cast<const float4*>(x);

  float s = 0.f;
  for (int sl = 0; sl < SLPP; ++sl) {
    const size_t base = (size_t)((part * SLPP + sl) * CH + c) * HW4;
    for (int i = tid; i < HW4; i += 256) {
      float4 v = x4[base + i];
      s += (v.x + v.y) + (v.z + v.w);
      if (fabsf(v.x - mu) >= t) { unsigned p = atomicAdd(&lcnt, 1u); if (p < LBUF) buf[p] = v.x; }
      if (fabsf(v.y - mu) >= t) { unsigned p = atomicAdd(&lcnt, 1u); if (p < LBUF) buf[p] = v.y; }
      if (fabsf(v.z - mu) >= t) { unsigned p = atomicAdd(&lcnt, 1u); if (p < LBUF) buf[p] = v.z; }
      if (fabsf(v.w - mu) >= t) { unsigned p = atomicAdd(&lcnt, 1u); if (p < LBUF) buf[p] = v.w; }
    }
  }
  for (int off = 32; off; off >>= 1) s += __shfl_down(s, off);
  const int lane = tid & 63, wid = tid >> 6;
  if (lane == 0) shs[wid] = s;
  __syncthreads();

  if (tid == 0) {
    sums[part * CH + c] = (shs[0] + shs[1]) + (shs[2] + shs[3]);
    gbase = atomicAdd(&cnt[c], lcnt);
    if (lcnt > (unsigned)LBUF) ovf[c] = 1u;
  }
  __syncthreads();

  const unsigned nw = lcnt < (unsigned)LBUF ? lcnt : (unsigned)LBUF;
  const unsigned gb = gbase;
  float* cc = cand + (size_t)c * cap;
  for (unsigned i = tid; i < nw; i += 256) {
    const unsigned p = gb + i;
    if (p < (unsigned)cap) cc[p] = buf[i];
  }
}

// ---------------------------------------------------------------------------
// k_select: per channel: exact mu, top-10 of |v-mu| from candidates (LDS)
// or full-channel rescue; fold into (sw, sb).  grid = CH, 256 threads.
// ---------------------------------------------------------------------------
__global__ __launch_bounds__(256) void k_select(const float* __restrict__ x,
                                                const float* __restrict__ sums,
                                                const unsigned* __restrict__ cnt,
                                                const unsigned* __restrict__ ovf,
                                                const float* __restrict__ cand,
                                                const float* __restrict__ weight,
                                                const float* __restrict__ bias,
                                                float* __restrict__ swg,
                                                float* __restrict__ sbg,
                                                int cap, float constv) {
  __shared__ float ls[CAPMAX];      // 32 KB (128-block kernel; occupancy moot)
  __shared__ float rwv[4];
  __shared__ int   rwi[4];
  const int c   = blockIdx.x;
  const int tid = threadIdx.x;
  const int lane = tid & 63, wid = tid >> 6;
  const float4* x4 = reinterpret_cast<const float4*>(x);

  float acc = 0.f;
  #pragma unroll
  for (int p = 0; p < PARTS; ++p) acc += sums[p * CH + c];
  const float mu = acc * (1.0f / ((float)NBATCH * (float)HWSZ));

  const unsigned n = cnt[c];
  const bool good = (n >= (unsigned)KTOP) && (n <= (unsigned)cap) &&
                    (n <= (unsigned)CAPMAX) && (ovf[c] == 0u);
  int m;
  if (good) {
    m = (int)n;
    const float* cc = cand + (size_t)c * cap;
    for (int i = tid; i < m; i += 256) ls[i] = fabsf(cc[i] - mu);
  } else {
    // rescue: full-channel per-thread top-10 chain (certified never needed
    // when cnt>=10 with uniform tau; exact regardless)
    float t0=-1.f,t1=-1.f,t2=-1.f,t3=-1.f,t4=-1.f,
          t5=-1.f,t6=-1.f,t7=-1.f,t8=-1.f,t9=-1.f;
    for (int sl = 0; sl < NBATCH; ++sl) {
      const size_t base = (size_t)(sl * CH + c) * HW4;
      for (int i = tid; i < HW4; i += 256) {
        float4 v = x4[base + i];
        float d0 = fabsf(v.x - mu), d1 = fabsf(v.y - mu);
        float d2 = fabsf(v.z - mu), d3 = fabsf(v.w - mu);
        CHAIN(d0); CHAIN(d1); CHAIN(d2); CHAIN(d3);
      }
    }
    ls[0*256+tid]=t0; ls[1*256+tid]=t1; ls[2*256+tid]=t2; ls[3*256+tid]=t3;
    ls[4*256+tid]=t4; ls[5*256+tid]=t5; ls[6*256+tid]=t6; ls[7*256+tid]=t7;
    ls[8*256+tid]=t8; ls[9*256+tid]=t9;
    m = KTOP * 256;
  }
  __syncthreads();

  float tot = 0.f;
  for (int it = 0; it < KTOP; ++it) {
    float best = -1.f; int bi = 0;
    for (int i = tid; i < m; i += 256) {
      float v = ls[i];
      if (v > best) { best = v; bi = i; }
    }
    for (int off = 32; off; off >>= 1) {
      float ov = __shfl_down(best, off);
      int   oi = __shfl_down(bi, off);
      if (ov > best) { best = ov; bi = oi; }
    }
    if (lane == 0) { rwv[wid] = best; rwi[wid] = bi; }
    __syncthreads();
    if (tid == 0) {
      float bb = rwv[0]; int bbi = rwi[0];
      for (int w = 1; w < 4; ++w) if (rwv[w] > bb) { bb = rwv[w]; bbi = rwi[w]; }
      tot += bb;
      ls[bbi] = -1.f;
    }
    __syncthreads();
  }

  if (tid == 0) {
    const float mtk = tot * (1.0f / KTOP) * constv;
    const float inv = 1.f / (mtk + EPSV);
    const float w   = inv * weight[c];
    swg[c] = w;
    sbg[c] = bias[c] - mu * w;
  }
}

// ---------------------------------------------------------------------------
// k_affine: pure stream, zero LDS, full occupancy.  grid = PARTS*CH, 256 thr.
// out = fma(x, w[c], b[c]); REGULAR stores (NT stores measured ~2.7 TB/s vs
// fillBuffer's 6.9 TB/s regular-store ceiling on gfx950).
// ---------------------------------------------------------------------------
__global__ __launch_bounds__(256) void k_affine(const float* __restrict__ x,
                                                const float* __restrict__ swg,
                                                const float* __restrict__ sbg,
                                                float* __restrict__ out) {
  const int bid  = blockIdx.x;
  const int c    = bid & (CH - 1);
  const int part = bid >> 7;
  const float w = swg[c], b = sbg[c];
  const float4* x4 = reinterpret_cast<const float4*>(x);
  float4* o4 = reinterpret_cast<float4*>(out);
  #pragma unroll
  for (int sl = 0; sl < SLPP; ++sl) {
    const size_t base = (size_t)((part * SLPP + sl) * CH + c) * HW4;
    for (int i = threadIdx.x; i < HW4; i += 256) {
      float4 v = x4[base + i];
      float4 r;
      r.x = fmaf(v.x, w, b);
      r.y = fmaf(v.y, w, b);
      r.z = fmaf(v.z, w, b);
      r.w = fmaf(v.w, w, b);
      o4[base + i] = r;
    }
  }
}

extern "C" void kernel_launch(void* const* d_in, const int* in_sizes, int n_in,
                              void* d_out, int out_size, void* d_ws, size_t ws_size,
                              hipStream_t stream) {
  const float* x      = (const float*)d_in[0];
  const float* weight = (const float*)d_in[1];
  const float* bias   = (const float*)d_in[2];
  float* out = (float*)d_out;
  float* ws  = (float*)d_ws;

  // ws layout (floats)
  float*    sums  = ws;                         // PARTS*CH = 2048
  float*    muhat = sums + PARTS * CH;          // 128
  float*    tauv  = muhat + CH;                 // 128
  float*    swg   = tauv + CH;                  // 128
  float*    sbg   = swg + CH;                   // 128
  unsigned* cnt   = (unsigned*)(sbg + CH);      // 128
  unsigned* ovf   = cnt + CH;                   // 128
  float*    cand  = (float*)(ovf + CH);         // CH*cap
  const size_t FIXED = (size_t)((float*)cand - ws);

  const size_t avail = ws_size / 4;
  int cap; float tauf;
  if      (avail >= FIXED + (size_t)CH * 8192) { cap = 8192; tauf = 0.72f; }
  else if (avail >= FIXED + (size_t)CH * 2048) { cap = 2048; tauf = 0.85f; }
  else                                         { cap = 1024; tauf = 0.90f; }

  const double M = (double)NBATCH * (double)HWSZ;
  const float constv =
      (float)(0.5 * (1.0 + sqrt(M_PI * log(4.0))) / sqrt(2.0 * log(M)));

  k_stats<<<CH, 256, 0, stream>>>(x, muhat, tauv, cnt, ovf, tauf);
  k_main<<<PARTS * CH, 256, 0, stream>>>(x, muhat, tauv, sums, cnt, ovf, cand, cap);
  k_select<<<CH, 256, 0, stream>>>(x, sums, cnt, ovf, cand, weight, bias,
                                   swg, sbg, cap, constv);
  k_affine<<<PARTS * CH, 256, 0, stream>>>(x, swg, sbg, out);
}